// Round 6
// baseline (1485.472 us; speedup 1.0000x reference)
//
#include <hip/hip_runtime.h>
#include <hip/hip_bf16.h>

// Attention_82841329205539: B=2, N=2048, C=768, H=12, D=64, window=129
// Inputs fp32 (dict order), OUTPUT fp32 ([B,N,C] flat) — ref returns float32.
#define Bsz   2
#define Nseq  2048
#define Cdim  768
#define Hh    12
#define Dd    64
#define HALF  64
#define WIN   129
#define SCALEF 0.125f

// ---------------------------------------------------------------------------
// Kernel 1: QKV projection.  qkv[bn, e] = sum_c x[bn,c] * w_qkv[e,c]
// e = three*768 + h*64 + d ; scatter into fp32 Q/K/V in [B,H,N,D] layout.
// ---------------------------------------------------------------------------
__global__ void qkv_gemm(const float* __restrict__ x, const float* __restrict__ w,
                         float* __restrict__ qf, float* __restrict__ kf,
                         float* __restrict__ vf)
{
    __shared__ float As[16][17];
    __shared__ float Bs[16][17];
    const int tx = threadIdx.x, ty = threadIdx.y;
    const int row = blockIdx.y * 16 + ty;       // bn in [0,4096)
    const int colBase = blockIdx.x * 16;        // e base
    const int col = colBase + tx;

    float acc = 0.f;
    for (int k0 = 0; k0 < Cdim; k0 += 16) {
        As[ty][tx] = x[(size_t)row * Cdim + k0 + tx];
        Bs[ty][tx] = w[(size_t)(colBase + ty) * Cdim + k0 + tx];
        __syncthreads();
#pragma unroll
        for (int kk = 0; kk < 16; ++kk)
            acc += As[ty][kk] * Bs[tx][kk];
        __syncthreads();
    }

    const int three = col / Cdim;
    const int rem   = col % Cdim;
    const int h = rem / Dd, d = rem % Dd;
    const int b = row / Nseq, n = row % Nseq;
    float* dst = (three == 0) ? qf : (three == 1 ? kf : vf);
    dst[(((size_t)(b * Hh + h) * Nseq) + n) * Dd + d] = acc;
}

// ---------------------------------------------------------------------------
// Kernel 2: sliding-window attention. One 128-thread block per (b,h,i).
// ---------------------------------------------------------------------------
__global__ void swin_attn(const float* __restrict__ qf, const float* __restrict__ kf,
                          const float* __restrict__ vf, float* __restrict__ ao)
{
    __shared__ float qs[Dd];
    __shared__ float sc[WIN];
    __shared__ float red[128];

    const int i   = blockIdx.x;
    const int bh  = blockIdx.y;
    const int tid = threadIdx.x;

    const float* qp = qf + ((size_t)bh * Nseq + i) * Dd;
    const float* kb = kf + (size_t)bh * Nseq * Dd;
    const float* vb = vf + (size_t)bh * Nseq * Dd;

    if (tid < Dd) qs[tid] = qp[tid];
    __syncthreads();

    const int jlo = max(0, i - HALF);
    const int jhi = min(Nseq - 1, i + HALF);
    const int wlen = jhi - jlo + 1;

    float lmax = -1e30f;
    for (int jj = tid; jj < wlen; jj += 128) {
        const float* kp = kb + (size_t)(jlo + jj) * Dd;
        float s = 0.f;
#pragma unroll
        for (int d = 0; d < Dd; ++d) s += qs[d] * kp[d];
        s *= SCALEF;
        sc[jj] = s;
        lmax = fmaxf(lmax, s);
    }
    red[tid] = lmax;
    __syncthreads();
    for (int off = 64; off > 0; off >>= 1) {
        if (tid < off) red[tid] = fmaxf(red[tid], red[tid + off]);
        __syncthreads();
    }
    const float m = red[0];
    __syncthreads();

    float lsum = 0.f;
    for (int jj = tid; jj < wlen; jj += 128) {
        float p = __expf(sc[jj] - m);
        sc[jj] = p;
        lsum += p;
    }
    red[tid] = lsum;
    __syncthreads();
    for (int off = 64; off > 0; off >>= 1) {
        if (tid < off) red[tid] += red[tid + off];
        __syncthreads();
    }
    const float inv = 1.f / red[0];
    __syncthreads();

    if (tid < Dd) {
        float acc = 0.f;
        for (int jj = 0; jj < wlen; ++jj)
            acc += sc[jj] * vb[(size_t)(jlo + jj) * Dd + tid];
        const int b = bh / Hh, h = bh % Hh;
        ao[((size_t)(b * Nseq + i)) * Cdim + h * Dd + tid] = acc * inv;
    }
}

// ---------------------------------------------------------------------------
// Kernel 3: output projection + bias -> FP32 output.
// ---------------------------------------------------------------------------
__global__ void proj_gemm(const float* __restrict__ a, const float* __restrict__ w,
                          const float* __restrict__ bias, float* __restrict__ out)
{
    __shared__ float As[16][17];
    __shared__ float Bs[16][17];
    const int tx = threadIdx.x, ty = threadIdx.y;
    const int row = blockIdx.y * 16 + ty;
    const int colBase = blockIdx.x * 16;
    const int col = colBase + tx;

    float acc = 0.f;
    for (int k0 = 0; k0 < Cdim; k0 += 16) {
        As[ty][tx] = a[(size_t)row * Cdim + k0 + tx];
        Bs[ty][tx] = w[(size_t)(colBase + ty) * Cdim + k0 + tx];
        __syncthreads();
#pragma unroll
        for (int kk = 0; kk < 16; ++kk)
            acc += As[ty][kk] * Bs[tx][kk];
        __syncthreads();
    }
    out[(size_t)row * Cdim + col] = acc + bias[col];   // FP32 write
}

// ---------------------------------------------------------------------------
extern "C" void kernel_launch(void* const* d_in, const int* in_sizes, int n_in,
                              void* d_out, int out_size, void* d_ws, size_t ws_size,
                              hipStream_t stream)
{
    const float* x      = (const float*)d_in[0];  // [B,N,C]   fp32
    const float* w_qkv  = (const float*)d_in[1];  // [3C,C]    fp32
    const float* w_proj = (const float*)d_in[2];  // [C,C]     fp32
    const float* b_proj = (const float*)d_in[3];  // [C]       fp32
    float* out = (float*)d_out;                   // [B,N,C]   fp32 (ref dtype!)

    const size_t qkv_elems = (size_t)Bsz * Hh * Nseq * Dd;  // 3,145,728
    float* qf = (float*)d_ws;
    float* kf = qf + qkv_elems;
    float* vf = kf + qkv_elems;
    float* ao = vf + qkv_elems;                 // [B,N,C] fp32
    // ws use: 4 * 3,145,728 * 4 B = 50.3 MB

    dim3 blk16(16, 16);
    qkv_gemm<<<dim3((3 * Cdim) / 16, (Bsz * Nseq) / 16), blk16, 0, stream>>>(
        x, w_qkv, qf, kf, vf);

    swin_attn<<<dim3(Nseq, Bsz * Hh), 128, 0, stream>>>(qf, kf, vf, ao);

    proj_gemm<<<dim3(Cdim / 16, (Bsz * Nseq) / 16), blk16, 0, stream>>>(
        ao, w_proj, b_proj, out);
}

// Round 7
// 809.163 us; speedup vs baseline: 1.8358x; 1.8358x over previous
//
#include <hip/hip_runtime.h>
#include <hip/hip_bf16.h>

// Attention_82841329205539: B=2, N=2048, C=768, H=12, D=64, window=129
// Inputs fp32 (dict order), OUTPUT fp32 [B,N,C]. PASSED baseline r6: 1485 us.
#define Bsz   2
#define Nseq  2048
#define Cdim  768
#define Hh    12
#define Dd    64
#define HALF  64
#define WIN   129
#define SCALEF 0.125f

// ---------------------------------------------------------------------------
// Register-blocked fp32 GEMM core: 128x128 tile, 256 threads, 8x8 per thread.
// A = data [M][768] row-major, Bmat = weights [Ncols][768] row-major (B^T GEMM).
// K-tile 16, single LDS buffer, double barrier.
// ---------------------------------------------------------------------------
#define LDP 132   // LDS row pad (floats): 4x33 -> float4-aligned, bank-spread

// ---------------------------------------------------------------------------
// Kernel 1: QKV projection -> scatter fp32 Q/K/V in [B,H,N,D] layout.
// grid (2304/128=18, 4096/128=32)
// ---------------------------------------------------------------------------
__global__ __launch_bounds__(256) void qkv_gemm(
    const float* __restrict__ x, const float* __restrict__ w,
    float* __restrict__ qf, float* __restrict__ kf, float* __restrict__ vf)
{
    __shared__ float As[16][LDP];
    __shared__ float Bs[16][LDP];

    const int t  = threadIdx.x;
    const int tx = t & 15;          // n-group: cols tx*8..+7
    const int ty = t >> 4;          // m-group: rows ty*8..+7
    const int row0 = blockIdx.y * 128;
    const int col0 = blockIdx.x * 128;

    const int lm = t >> 1;          // 0..127: tile row loaded by this thread
    const int lk = (t & 1) * 8;     // 0 or 8: k-offset

    float acc[8][8] = {};

    for (int k0 = 0; k0 < Cdim; k0 += 16) {
        float4 a0 = *(const float4*)&x[(size_t)(row0 + lm) * Cdim + k0 + lk];
        float4 a1 = *(const float4*)&x[(size_t)(row0 + lm) * Cdim + k0 + lk + 4];
        float4 b0 = *(const float4*)&w[(size_t)(col0 + lm) * Cdim + k0 + lk];
        float4 b1 = *(const float4*)&w[(size_t)(col0 + lm) * Cdim + k0 + lk + 4];
        __syncthreads();            // previous tile's readers done
        As[lk+0][lm] = a0.x; As[lk+1][lm] = a0.y; As[lk+2][lm] = a0.z; As[lk+3][lm] = a0.w;
        As[lk+4][lm] = a1.x; As[lk+5][lm] = a1.y; As[lk+6][lm] = a1.z; As[lk+7][lm] = a1.w;
        Bs[lk+0][lm] = b0.x; Bs[lk+1][lm] = b0.y; Bs[lk+2][lm] = b0.z; Bs[lk+3][lm] = b0.w;
        Bs[lk+4][lm] = b1.x; Bs[lk+5][lm] = b1.y; Bs[lk+6][lm] = b1.z; Bs[lk+7][lm] = b1.w;
        __syncthreads();
#pragma unroll
        for (int k = 0; k < 16; ++k) {
            float4 fa0 = *(const float4*)&As[k][ty * 8];
            float4 fa1 = *(const float4*)&As[k][ty * 8 + 4];
            float4 fb0 = *(const float4*)&Bs[k][tx * 8];
            float4 fb1 = *(const float4*)&Bs[k][tx * 8 + 4];
            float fa[8] = {fa0.x, fa0.y, fa0.z, fa0.w, fa1.x, fa1.y, fa1.z, fa1.w};
            float fb[8] = {fb0.x, fb0.y, fb0.z, fb0.w, fb1.x, fb1.y, fb1.z, fb1.w};
#pragma unroll
            for (int ri = 0; ri < 8; ++ri)
#pragma unroll
                for (int ci = 0; ci < 8; ++ci)
                    acc[ri][ci] += fa[ri] * fb[ci];
        }
    }

    // Epilogue: scatter. Block spans one `three` (768%128==0); each thread's
    // 8 cols stay inside one head (8 | 64).
    const int colT  = col0 + tx * 8;
    const int three = colT / Cdim;
    const int rem   = colT % Cdim;
    const int h     = rem / Dd;
    const int d0    = rem % Dd;
    const int b     = row0 / Nseq;          // 2048 % 128 == 0 -> block-uniform
    float* dst = (three == 0) ? qf : (three == 1 ? kf : vf);

#pragma unroll
    for (int ri = 0; ri < 8; ++ri) {
        const int n = (row0 % Nseq) + ty * 8 + ri;
        float* p = &dst[(((size_t)(b * Hh + h) * Nseq) + n) * Dd + d0];
        *(float4*)&p[0] = make_float4(acc[ri][0], acc[ri][1], acc[ri][2], acc[ri][3]);
        *(float4*)&p[4] = make_float4(acc[ri][4], acc[ri][5], acc[ri][6], acc[ri][7]);
    }
}

// ---------------------------------------------------------------------------
// Kernel 2: sliding-window attention. Block (128 thr) per (b,h,i).
// PV split 2-way across the window for 2x PV parallelism.
// ---------------------------------------------------------------------------
__global__ __launch_bounds__(128) void swin_attn(
    const float* __restrict__ qf, const float* __restrict__ kf,
    const float* __restrict__ vf, float* __restrict__ ao)
{
    __shared__ float qs[Dd];
    __shared__ float sc[WIN];
    __shared__ float red[128];

    const int i   = blockIdx.x;
    const int bh  = blockIdx.y;
    const int tid = threadIdx.x;

    const float* qp = qf + ((size_t)bh * Nseq + i) * Dd;
    const float* kb = kf + (size_t)bh * Nseq * Dd;
    const float* vb = vf + (size_t)bh * Nseq * Dd;

    if (tid < Dd) qs[tid] = qp[tid];
    __syncthreads();

    const int jlo = max(0, i - HALF);
    const int jhi = min(Nseq - 1, i + HALF);
    const int wlen = jhi - jlo + 1;

    float lmax = -1e30f;
    for (int jj = tid; jj < wlen; jj += 128) {
        const float* kp = kb + (size_t)(jlo + jj) * Dd;
        float s = 0.f;
#pragma unroll
        for (int d = 0; d < Dd; ++d) s += qs[d] * kp[d];
        s *= SCALEF;
        sc[jj] = s;
        lmax = fmaxf(lmax, s);
    }
    red[tid] = lmax;
    __syncthreads();
    for (int off = 64; off > 0; off >>= 1) {
        if (tid < off) red[tid] = fmaxf(red[tid], red[tid + off]);
        __syncthreads();
    }
    const float m = red[0];
    __syncthreads();

    float lsum = 0.f;
    for (int jj = tid; jj < wlen; jj += 128) {
        float p = __expf(sc[jj] - m);
        sc[jj] = p;
        lsum += p;
    }
    red[tid] = lsum;
    __syncthreads();
    for (int off = 64; off > 0; off >>= 1) {
        if (tid < off) red[tid] += red[tid + off];
        __syncthreads();
    }
    const float inv = 1.f / red[0];
    __syncthreads();

    // PV: thread (half, d) accumulates jj = half, half+2, ...
    const int d    = tid & 63;
    const int half = tid >> 6;
    float acc = 0.f;
    for (int jj = half; jj < wlen; jj += 2)
        acc += sc[jj] * vb[(size_t)(jlo + jj) * Dd + d];
    red[tid] = acc;
    __syncthreads();
    if (tid < Dd) {
        const int b = bh / Hh, h = bh % Hh;
        ao[((size_t)(b * Nseq + i)) * Cdim + h * Dd + tid] =
            (red[tid] + red[tid + 64]) * inv;
    }
}

// ---------------------------------------------------------------------------
// Kernel 3: output projection + bias -> FP32 out. grid (768/128=6, 32).
// ---------------------------------------------------------------------------
__global__ __launch_bounds__(256) void proj_gemm(
    const float* __restrict__ a, const float* __restrict__ w,
    const float* __restrict__ bias, float* __restrict__ out)
{
    __shared__ float As[16][LDP];
    __shared__ float Bs[16][LDP];

    const int t  = threadIdx.x;
    const int tx = t & 15;
    const int ty = t >> 4;
    const int row0 = blockIdx.y * 128;
    const int col0 = blockIdx.x * 128;

    const int lm = t >> 1;
    const int lk = (t & 1) * 8;

    float acc[8][8] = {};

    for (int k0 = 0; k0 < Cdim; k0 += 16) {
        float4 a0 = *(const float4*)&a[(size_t)(row0 + lm) * Cdim + k0 + lk];
        float4 a1 = *(const float4*)&a[(size_t)(row0 + lm) * Cdim + k0 + lk + 4];
        float4 b0 = *(const float4*)&w[(size_t)(col0 + lm) * Cdim + k0 + lk];
        float4 b1 = *(const float4*)&w[(size_t)(col0 + lm) * Cdim + k0 + lk + 4];
        __syncthreads();
        As[lk+0][lm] = a0.x; As[lk+1][lm] = a0.y; As[lk+2][lm] = a0.z; As[lk+3][lm] = a0.w;
        As[lk+4][lm] = a1.x; As[lk+5][lm] = a1.y; As[lk+6][lm] = a1.z; As[lk+7][lm] = a1.w;
        Bs[lk+0][lm] = b0.x; Bs[lk+1][lm] = b0.y; Bs[lk+2][lm] = b0.z; Bs[lk+3][lm] = b0.w;
        Bs[lk+4][lm] = b1.x; Bs[lk+5][lm] = b1.y; Bs[lk+6][lm] = b1.z; Bs[lk+7][lm] = b1.w;
        __syncthreads();
#pragma unroll
        for (int k = 0; k < 16; ++k) {
            float4 fa0 = *(const float4*)&As[k][ty * 8];
            float4 fa1 = *(const float4*)&As[k][ty * 8 + 4];
            float4 fb0 = *(const float4*)&Bs[k][tx * 8];
            float4 fb1 = *(const float4*)&Bs[k][tx * 8 + 4];
            float fa[8] = {fa0.x, fa0.y, fa0.z, fa0.w, fa1.x, fa1.y, fa1.z, fa1.w};
            float fb[8] = {fb0.x, fb0.y, fb0.z, fb0.w, fb1.x, fb1.y, fb1.z, fb1.w};
#pragma unroll
            for (int ri = 0; ri < 8; ++ri)
#pragma unroll
                for (int ci = 0; ci < 8; ++ci)
                    acc[ri][ci] += fa[ri] * fb[ci];
        }
    }

    const int colT = col0 + tx * 8;
    float4 bv0 = *(const float4*)&bias[colT];
    float4 bv1 = *(const float4*)&bias[colT + 4];
#pragma unroll
    for (int ri = 0; ri < 8; ++ri) {
        float* p = &out[(size_t)(row0 + ty * 8 + ri) * Cdim + colT];
        *(float4*)&p[0] = make_float4(acc[ri][0] + bv0.x, acc[ri][1] + bv0.y,
                                      acc[ri][2] + bv0.z, acc[ri][3] + bv0.w);
        *(float4*)&p[4] = make_float4(acc[ri][4] + bv1.x, acc[ri][5] + bv1.y,
                                      acc[ri][6] + bv1.z, acc[ri][7] + bv1.w);
    }
}

// ---------------------------------------------------------------------------
extern "C" void kernel_launch(void* const* d_in, const int* in_sizes, int n_in,
                              void* d_out, int out_size, void* d_ws, size_t ws_size,
                              hipStream_t stream)
{
    const float* x      = (const float*)d_in[0];  // [B,N,C]   fp32
    const float* w_qkv  = (const float*)d_in[1];  // [3C,C]    fp32
    const float* w_proj = (const float*)d_in[2];  // [C,C]     fp32
    const float* b_proj = (const float*)d_in[3];  // [C]       fp32
    float* out = (float*)d_out;                   // [B,N,C]   fp32

    const size_t qkv_elems = (size_t)Bsz * Hh * Nseq * Dd;  // 3,145,728
    float* qf = (float*)d_ws;
    float* kf = qf + qkv_elems;
    float* vf = kf + qkv_elems;
    float* ao = vf + qkv_elems;                 // [B,N,C] fp32

    qkv_gemm<<<dim3((3 * Cdim) / 128, (Bsz * Nseq) / 128), 256, 0, stream>>>(
        x, w_qkv, qf, kf, vf);

    swin_attn<<<dim3(Nseq, Bsz * Hh), 128, 0, stream>>>(qf, kf, vf, ao);

    proj_gemm<<<dim3(Cdim / 128, (Bsz * Nseq) / 128), 256, 0, stream>>>(
        ao, w_proj, b_proj, out);
}

// Round 8
// 444.368 us; speedup vs baseline: 3.3429x; 1.8209x over previous
//
#include <hip/hip_runtime.h>
#include <hip/hip_bf16.h>

// Attention_82841329205539: B=2, N=2048, C=768, H=12, D=64, window=129
// Inputs fp32 (dict order), OUTPUT fp32 [B,N,C]. r6: 1485us, r7: 809us.
#define Bsz   2
#define Nseq  2048
#define Cdim  768
#define Hh    12
#define Dd    64
#define HALF  64
#define WIN   129
#define SCALEF 0.125f

#define LDP 132   // GEMM LDS row pad (floats)

// bf16 pack/unpack helpers (RNE pack; unpack = shift)
__device__ __forceinline__ unsigned short f2bf(float f) {
    unsigned int u = __float_as_uint(f);
    u = (u + 0x7FFFu + ((u >> 16) & 1u)) >> 16;
    return (unsigned short)u;
}
__device__ __forceinline__ float lo2f(unsigned int u) { return __uint_as_float(u << 16); }
__device__ __forceinline__ float hi2f(unsigned int u) { return __uint_as_float(u & 0xffff0000u); }

// ---------------------------------------------------------------------------
// Kernel 1: QKV projection (128x128 tile, 8x8/thread) -> fp32 Q/K/V [B,H,N,D].
// ---------------------------------------------------------------------------
__global__ __launch_bounds__(256) void qkv_gemm(
    const float* __restrict__ x, const float* __restrict__ w,
    float* __restrict__ qf, float* __restrict__ kf, float* __restrict__ vf)
{
    __shared__ float As[16][LDP];
    __shared__ float Bs[16][LDP];

    const int t  = threadIdx.x;
    const int tx = t & 15;
    const int ty = t >> 4;
    const int row0 = blockIdx.y * 128;
    const int col0 = blockIdx.x * 128;

    const int lm = t >> 1;
    const int lk = (t & 1) * 8;

    float acc[8][8] = {};

    for (int k0 = 0; k0 < Cdim; k0 += 16) {
        float4 a0 = *(const float4*)&x[(size_t)(row0 + lm) * Cdim + k0 + lk];
        float4 a1 = *(const float4*)&x[(size_t)(row0 + lm) * Cdim + k0 + lk + 4];
        float4 b0 = *(const float4*)&w[(size_t)(col0 + lm) * Cdim + k0 + lk];
        float4 b1 = *(const float4*)&w[(size_t)(col0 + lm) * Cdim + k0 + lk + 4];
        __syncthreads();
        As[lk+0][lm] = a0.x; As[lk+1][lm] = a0.y; As[lk+2][lm] = a0.z; As[lk+3][lm] = a0.w;
        As[lk+4][lm] = a1.x; As[lk+5][lm] = a1.y; As[lk+6][lm] = a1.z; As[lk+7][lm] = a1.w;
        Bs[lk+0][lm] = b0.x; Bs[lk+1][lm] = b0.y; Bs[lk+2][lm] = b0.z; Bs[lk+3][lm] = b0.w;
        Bs[lk+4][lm] = b1.x; Bs[lk+5][lm] = b1.y; Bs[lk+6][lm] = b1.z; Bs[lk+7][lm] = b1.w;
        __syncthreads();
#pragma unroll
        for (int k = 0; k < 16; ++k) {
            float4 fa0 = *(const float4*)&As[k][ty * 8];
            float4 fa1 = *(const float4*)&As[k][ty * 8 + 4];
            float4 fb0 = *(const float4*)&Bs[k][tx * 8];
            float4 fb1 = *(const float4*)&Bs[k][tx * 8 + 4];
            float fa[8] = {fa0.x, fa0.y, fa0.z, fa0.w, fa1.x, fa1.y, fa1.z, fa1.w};
            float fb[8] = {fb0.x, fb0.y, fb0.z, fb0.w, fb1.x, fb1.y, fb1.z, fb1.w};
#pragma unroll
            for (int ri = 0; ri < 8; ++ri)
#pragma unroll
                for (int ci = 0; ci < 8; ++ci)
                    acc[ri][ci] += fa[ri] * fb[ci];
        }
    }

    const int colT  = col0 + tx * 8;
    const int three = colT / Cdim;
    const int rem   = colT % Cdim;
    const int h     = rem / Dd;
    const int d0    = rem % Dd;
    const int b     = row0 / Nseq;
    float* dst = (three == 0) ? qf : (three == 1 ? kf : vf);

#pragma unroll
    for (int ri = 0; ri < 8; ++ri) {
        const int n = (row0 % Nseq) + ty * 8 + ri;
        float* p = &dst[(((size_t)(b * Hh + h) * Nseq) + n) * Dd + d0];
        *(float4*)&p[0] = make_float4(acc[ri][0], acc[ri][1], acc[ri][2], acc[ri][3]);
        *(float4*)&p[4] = make_float4(acc[ri][4], acc[ri][5], acc[ri][6], acc[ri][7]);
    }
}

// ---------------------------------------------------------------------------
// Kernel 2 v2: tiled sliding-window attention.
// 32 queries/block; K/V window (160 rows) staged ONCE in LDS as bf16 and
// reused by all 32 queries. 8 lanes per query (same wave) -> shuffle softmax.
// Grid (Nseq/32=64, B*H=24), 256 threads. LDS 61.4 KB -> 2 blocks/CU.
// ---------------------------------------------------------------------------
#define TQ   32
#define ROWS 160     // TQ + 2*HALF
#define KST  72      // bf16 row stride: 144 B = 9x16 (aligned b128 chunks)
#define SST  168     // sc row stride: 336 B, 16B-aligned chunks

__global__ __launch_bounds__(256) void swin_attn(
    const float* __restrict__ qf, const float* __restrict__ kf,
    const float* __restrict__ vf, float* __restrict__ ao)
{
    __shared__ __align__(16) unsigned short Qs[TQ][KST];     //  4608 B
    __shared__ __align__(16) unsigned short Ks[ROWS][KST];   // 23040 B
    __shared__ __align__(16) unsigned short Vs[ROWS][KST];   // 23040 B
    __shared__ __align__(16) unsigned short sc[TQ][SST];     // 10752 B

    const int t  = threadIdx.x;
    const int bh = blockIdx.y;
    const int b  = bh / Hh, h = bh % Hh;
    const int i0 = blockIdx.x * TQ;

    // ---- stage Q (32 rows) + K/V (160 rows each) as bf16; OOB rows -> 0
    for (int F = t; F < 352 * 16; F += 256) {
        const int r  = F >> 4;          // virtual row 0..351
        const int c4 = F & 15;          // 4-float chunk
        const float* base = nullptr;
        unsigned short* dst;
        if (r < 32) {
            base = qf + ((size_t)bh * Nseq + (i0 + r)) * Dd;
            dst = &Qs[r][c4 * 4];
        } else if (r < 192) {
            const int g = i0 - HALF + (r - 32);
            if (g >= 0 && g < Nseq) base = kf + ((size_t)bh * Nseq + g) * Dd;
            dst = &Ks[r - 32][c4 * 4];
        } else {
            const int g = i0 - HALF + (r - 192);
            if (g >= 0 && g < Nseq) base = vf + ((size_t)bh * Nseq + g) * Dd;
            dst = &Vs[r - 192][c4 * 4];
        }
        float4 v = make_float4(0.f, 0.f, 0.f, 0.f);
        if (base) v = *(const float4*)&base[c4 * 4];
        union { unsigned short us[4]; uint2 u2; } pk;
        pk.us[0] = f2bf(v.x); pk.us[1] = f2bf(v.y);
        pk.us[2] = f2bf(v.z); pk.us[3] = f2bf(v.w);
        *(uint2*)dst = pk.u2;
    }
    __syncthreads();

    const int q = t >> 3;        // owned query (0..31)
    const int s = t & 7;         // lane within query team
    const int i = i0 + q;

    // Q row -> registers (fp32)
    float qreg[64];
#pragma unroll
    for (int c = 0; c < 8; ++c) {
        uint4 u = *(const uint4*)&Qs[q][c * 8];
        qreg[c*8+0] = lo2f(u.x); qreg[c*8+1] = hi2f(u.x);
        qreg[c*8+2] = lo2f(u.y); qreg[c*8+3] = hi2f(u.y);
        qreg[c*8+4] = lo2f(u.z); qreg[c*8+5] = hi2f(u.z);
        qreg[c*8+6] = lo2f(u.w); qreg[c*8+7] = hi2f(u.w);
    }

    // ---- scores: lane covers j = s + 8m, m = 0..19
    float sreg[20];
    float lmax = -1e30f;
#pragma unroll
    for (int m = 0; m < 20; ++m) {
        const int j = s + 8 * m;
        const int g = i0 - HALF + j;
        const bool valid = (j >= q) && (j <= q + 2 * HALF) && (g >= 0) && (g < Nseq);
        float dot = 0.f;
#pragma unroll
        for (int c = 0; c < 8; ++c) {
            uint4 u = *(const uint4*)&Ks[j][c * 8];
            dot += qreg[c*8+0]*lo2f(u.x) + qreg[c*8+1]*hi2f(u.x)
                 + qreg[c*8+2]*lo2f(u.y) + qreg[c*8+3]*hi2f(u.y)
                 + qreg[c*8+4]*lo2f(u.z) + qreg[c*8+5]*hi2f(u.z)
                 + qreg[c*8+6]*lo2f(u.w) + qreg[c*8+7]*hi2f(u.w);
        }
        sreg[m] = valid ? dot * SCALEF : -1e30f;
        lmax = fmaxf(lmax, sreg[m]);
    }
    lmax = fmaxf(lmax, __shfl_xor(lmax, 1));
    lmax = fmaxf(lmax, __shfl_xor(lmax, 2));
    lmax = fmaxf(lmax, __shfl_xor(lmax, 4));

    float lsum = 0.f;
#pragma unroll
    for (int m = 0; m < 20; ++m) {
        const float p = (sreg[m] > -1e29f) ? __expf(sreg[m] - lmax) : 0.f;
        lsum += p;
        sc[q][s + 8 * m] = f2bf(p);
    }
    lsum += __shfl_xor(lsum, 1);
    lsum += __shfl_xor(lsum, 2);
    lsum += __shfl_xor(lsum, 4);
    const float inv = 1.f / lsum;

    __syncthreads();   // sc visible (same-wave anyway; ordering safety)

    // ---- PV: lane owns d-range d0..d0+7; iterate j chunks of 8
    const int d0 = s * 8;
    float acc[8] = {};
    for (int m0 = 0; m0 < 20; ++m0) {
        const int jb = m0 * 8;
        if (jb + 7 < q || jb > q + 2 * HALF) continue;   // fully outside window
        uint4 up = *(const uint4*)&sc[q][jb];
        const float pv[8] = {lo2f(up.x), hi2f(up.x), lo2f(up.y), hi2f(up.y),
                             lo2f(up.z), hi2f(up.z), lo2f(up.w), hi2f(up.w)};
#pragma unroll
        for (int jj = 0; jj < 8; ++jj) {
            uint4 uv = *(const uint4*)&Vs[jb + jj][d0];
            const float p = pv[jj];
            acc[0] += p * lo2f(uv.x); acc[1] += p * hi2f(uv.x);
            acc[2] += p * lo2f(uv.y); acc[3] += p * hi2f(uv.y);
            acc[4] += p * lo2f(uv.z); acc[5] += p * hi2f(uv.z);
            acc[6] += p * lo2f(uv.w); acc[7] += p * hi2f(uv.w);
        }
    }

    float* orow = &ao[((size_t)(b * Nseq + i)) * Cdim + h * Dd + d0];
    *(float4*)&orow[0] = make_float4(acc[0]*inv, acc[1]*inv, acc[2]*inv, acc[3]*inv);
    *(float4*)&orow[4] = make_float4(acc[4]*inv, acc[5]*inv, acc[6]*inv, acc[7]*inv);
}

// ---------------------------------------------------------------------------
// Kernel 3: output projection + bias -> FP32 out. grid (6, 32).
// ---------------------------------------------------------------------------
__global__ __launch_bounds__(256) void proj_gemm(
    const float* __restrict__ a, const float* __restrict__ w,
    const float* __restrict__ bias, float* __restrict__ out)
{
    __shared__ float As[16][LDP];
    __shared__ float Bs[16][LDP];

    const int t  = threadIdx.x;
    const int tx = t & 15;
    const int ty = t >> 4;
    const int row0 = blockIdx.y * 128;
    const int col0 = blockIdx.x * 128;

    const int lm = t >> 1;
    const int lk = (t & 1) * 8;

    float acc[8][8] = {};

    for (int k0 = 0; k0 < Cdim; k0 += 16) {
        float4 a0 = *(const float4*)&a[(size_t)(row0 + lm) * Cdim + k0 + lk];
        float4 a1 = *(const float4*)&a[(size_t)(row0 + lm) * Cdim + k0 + lk + 4];
        float4 b0 = *(const float4*)&w[(size_t)(col0 + lm) * Cdim + k0 + lk];
        float4 b1 = *(const float4*)&w[(size_t)(col0 + lm) * Cdim + k0 + lk + 4];
        __syncthreads();
        As[lk+0][lm] = a0.x; As[lk+1][lm] = a0.y; As[lk+2][lm] = a0.z; As[lk+3][lm] = a0.w;
        As[lk+4][lm] = a1.x; As[lk+5][lm] = a1.y; As[lk+6][lm] = a1.z; As[lk+7][lm] = a1.w;
        Bs[lk+0][lm] = b0.x; Bs[lk+1][lm] = b0.y; Bs[lk+2][lm] = b0.z; Bs[lk+3][lm] = b0.w;
        Bs[lk+4][lm] = b1.x; Bs[lk+5][lm] = b1.y; Bs[lk+6][lm] = b1.z; Bs[lk+7][lm] = b1.w;
        __syncthreads();
#pragma unroll
        for (int k = 0; k < 16; ++k) {
            float4 fa0 = *(const float4*)&As[k][ty * 8];
            float4 fa1 = *(const float4*)&As[k][ty * 8 + 4];
            float4 fb0 = *(const float4*)&Bs[k][tx * 8];
            float4 fb1 = *(const float4*)&Bs[k][tx * 8 + 4];
            float fa[8] = {fa0.x, fa0.y, fa0.z, fa0.w, fa1.x, fa1.y, fa1.z, fa1.w};
            float fb[8] = {fb0.x, fb0.y, fb0.z, fb0.w, fb1.x, fb1.y, fb1.z, fb1.w};
#pragma unroll
            for (int ri = 0; ri < 8; ++ri)
#pragma unroll
                for (int ci = 0; ci < 8; ++ci)
                    acc[ri][ci] += fa[ri] * fb[ci];
        }
    }

    const int colT = col0 + tx * 8;
    float4 bv0 = *(const float4*)&bias[colT];
    float4 bv1 = *(const float4*)&bias[colT + 4];
#pragma unroll
    for (int ri = 0; ri < 8; ++ri) {
        float* p = &out[(size_t)(row0 + ty * 8 + ri) * Cdim + colT];
        *(float4*)&p[0] = make_float4(acc[ri][0] + bv0.x, acc[ri][1] + bv0.y,
                                      acc[ri][2] + bv0.z, acc[ri][3] + bv0.w);
        *(float4*)&p[4] = make_float4(acc[ri][4] + bv1.x, acc[ri][5] + bv1.y,
                                      acc[ri][6] + bv1.z, acc[ri][7] + bv1.w);
    }
}

// ---------------------------------------------------------------------------
extern "C" void kernel_launch(void* const* d_in, const int* in_sizes, int n_in,
                              void* d_out, int out_size, void* d_ws, size_t ws_size,
                              hipStream_t stream)
{
    const float* x      = (const float*)d_in[0];
    const float* w_qkv  = (const float*)d_in[1];
    const float* w_proj = (const float*)d_in[2];
    const float* b_proj = (const float*)d_in[3];
    float* out = (float*)d_out;

    const size_t qkv_elems = (size_t)Bsz * Hh * Nseq * Dd;  // 3,145,728
    float* qf = (float*)d_ws;
    float* kf = qf + qkv_elems;
    float* vf = kf + qkv_elems;
    float* ao = vf + qkv_elems;

    qkv_gemm<<<dim3((3 * Cdim) / 128, (Bsz * Nseq) / 128), 256, 0, stream>>>(
        x, w_qkv, qf, kf, vf);

    swin_attn<<<dim3(Nseq / TQ, Bsz * Hh), 256, 0, stream>>>(qf, kf, vf, ao);

    proj_gemm<<<dim3(Cdim / 128, (Bsz * Nseq) / 128), 256, 0, stream>>>(
        ao, w_proj, b_proj, out);
}

// Round 10
// 270.221 us; speedup vs baseline: 5.4973x; 1.6445x over previous
//
#include <hip/hip_runtime.h>
#include <hip/hip_bf16.h>

// Attention_82841329205539: B=2, N=2048, C=768, H=12, D=64, window=129
// Inputs fp32 (dict order), OUTPUT fp32 [B,N,C]. r6:1485 r7:809 r8:444 us.
// r9 FAILED: ws stride bug (1,048,576 vs 3,145,728) -> Q/K/V buffers aliased.
#define Bsz   2
#define Nseq  2048
#define Cdim  768
#define Hh    12
#define Dd    64
#define HALF  64
#define SCALEF 0.125f

typedef __attribute__((ext_vector_type(8))) short short8;   // 8 bf16 = 4 VGPR
typedef __attribute__((ext_vector_type(4))) float f32x4;

__device__ __forceinline__ unsigned short f2bf(float f) {
    unsigned int u = __float_as_uint(f);
    u = (u + 0x7FFFu + ((u >> 16) & 1u)) >> 16;
    return (unsigned short)u;
}
__device__ __forceinline__ float lo2f(unsigned int u) { return __uint_as_float(u << 16); }
__device__ __forceinline__ float hi2f(unsigned int u) { return __uint_as_float(u & 0xffff0000u); }

// ---------------------------------------------------------------------------
// fp32 -> bf16 elementwise convert (n divisible by 4)
// ---------------------------------------------------------------------------
__global__ __launch_bounds__(256) void f32_to_bf16(
    const float* __restrict__ src, unsigned short* __restrict__ dst, int n)
{
    const int i = (blockIdx.x * 256 + threadIdx.x) * 4;
    if (i < n) {
        float4 v = *(const float4*)&src[i];
        union { unsigned short us[4]; uint2 u2; } pk;
        pk.us[0] = f2bf(v.x); pk.us[1] = f2bf(v.y);
        pk.us[2] = f2bf(v.z); pk.us[3] = f2bf(v.w);
        *(uint2*)&dst[i] = pk.u2;
    }
}

// ---------------------------------------------------------------------------
// MFMA GEMM: 128x128 tile, 256 thr = 4 waves (2x2 of 64x64), each wave 4x4
// MFMA 16x16x32 bf16, fp32 acc. A[M][768], W[N][768] bf16 row-major;
// out[m][n] = sum_k A[m][k]*W[n][k]. BK=64, single LDS buffer.
// Layouts (m89/m91/m120 verified): A/B frag elem j = M[row=lane&15][k=quad*8+j];
// C/D: m=quad*4+reg, n=lane&15.
// ---------------------------------------------------------------------------
#define BK  64
#define AST 72    // LDS row stride (bf16): 144 B

// ---------------------------------------------------------------------------
// Kernel: QKV projection MFMA -> bf16 Q/K/V in [B,H,N,D]. grid (18, 32).
// ---------------------------------------------------------------------------
__global__ __launch_bounds__(256) void qkv_mfma(
    const unsigned short* __restrict__ Ab, const unsigned short* __restrict__ Wb,
    unsigned short* __restrict__ qb, unsigned short* __restrict__ kb,
    unsigned short* __restrict__ vb)
{
    __shared__ __align__(16) unsigned short Al[128][AST];
    __shared__ __align__(16) unsigned short Bl[128][AST];

    const int t    = threadIdx.x;
    const int row0 = blockIdx.y * 128;
    const int col0 = blockIdx.x * 128;
    const int lane = t & 63, wave = t >> 6;
    const int wm = wave >> 1, wn = wave & 1;
    const int ln = lane & 15, quad = lane >> 4;

    f32x4 acc[4][4] = {};

    for (int k0 = 0; k0 < Cdim; k0 += BK) {
        uint4 ra[4], rb[4];
#pragma unroll
        for (int j = 0; j < 4; ++j) {
            const int F = t + j * 256, r = F >> 3, c = F & 7;
            ra[j] = *(const uint4*)&Ab[(size_t)(row0 + r) * Cdim + k0 + c * 8];
            rb[j] = *(const uint4*)&Wb[(size_t)(col0 + r) * Cdim + k0 + c * 8];
        }
        __syncthreads();
#pragma unroll
        for (int j = 0; j < 4; ++j) {
            const int F = t + j * 256, r = F >> 3, c = F & 7;
            *(uint4*)&Al[r][c * 8] = ra[j];
            *(uint4*)&Bl[r][c * 8] = rb[j];
        }
        __syncthreads();
#pragma unroll
        for (int kk = 0; kk < BK; kk += 32) {
            short8 af[4], bf[4];
#pragma unroll
            for (int mi = 0; mi < 4; ++mi)
                af[mi] = *(const short8*)&Al[wm*64 + mi*16 + ln][kk + quad*8];
#pragma unroll
            for (int ni = 0; ni < 4; ++ni)
                bf[ni] = *(const short8*)&Bl[wn*64 + ni*16 + ln][kk + quad*8];
#pragma unroll
            for (int mi = 0; mi < 4; ++mi)
#pragma unroll
                for (int ni = 0; ni < 4; ++ni)
                    acc[mi][ni] = __builtin_amdgcn_mfma_f32_16x16x32_bf16(
                        af[mi], bf[ni], acc[mi][ni], 0, 0, 0);
        }
    }

    // Epilogue: scatter bf16 into Q/K/V [B,H,N,D].
    const int three = col0 / Cdim;                       // block-uniform
    const int hh    = ((col0 % Cdim) + wn * 64) / Dd;    // wave-uniform
    unsigned short* dst = (three == 0) ? qb : (three == 1 ? kb : vb);
    const int b = row0 / Nseq;
    const size_t headbase = ((size_t)(b * Hh + hh) * Nseq) * Dd;
#pragma unroll
    for (int mi = 0; mi < 4; ++mi)
#pragma unroll
        for (int ni = 0; ni < 4; ++ni) {
            const int d = ni * 16 + ln;
#pragma unroll
            for (int reg = 0; reg < 4; ++reg) {
                const int n = (row0 % Nseq) + wm*64 + mi*16 + quad*4 + reg;
                dst[headbase + (size_t)n * Dd + d] = f2bf(acc[mi][ni][reg]);
            }
        }
}

// ---------------------------------------------------------------------------
// Kernel: output projection MFMA + bias -> fp32 out. grid (6, 32).
// ---------------------------------------------------------------------------
__global__ __launch_bounds__(256) void proj_mfma(
    const unsigned short* __restrict__ Ab, const unsigned short* __restrict__ Wb,
    const float* __restrict__ bias, float* __restrict__ out)
{
    __shared__ __align__(16) unsigned short Al[128][AST];
    __shared__ __align__(16) unsigned short Bl[128][AST];

    const int t    = threadIdx.x;
    const int row0 = blockIdx.y * 128;
    const int col0 = blockIdx.x * 128;
    const int lane = t & 63, wave = t >> 6;
    const int wm = wave >> 1, wn = wave & 1;
    const int ln = lane & 15, quad = lane >> 4;

    f32x4 acc[4][4] = {};

    for (int k0 = 0; k0 < Cdim; k0 += BK) {
        uint4 ra[4], rb[4];
#pragma unroll
        for (int j = 0; j < 4; ++j) {
            const int F = t + j * 256, r = F >> 3, c = F & 7;
            ra[j] = *(const uint4*)&Ab[(size_t)(row0 + r) * Cdim + k0 + c * 8];
            rb[j] = *(const uint4*)&Wb[(size_t)(col0 + r) * Cdim + k0 + c * 8];
        }
        __syncthreads();
#pragma unroll
        for (int j = 0; j < 4; ++j) {
            const int F = t + j * 256, r = F >> 3, c = F & 7;
            *(uint4*)&Al[r][c * 8] = ra[j];
            *(uint4*)&Bl[r][c * 8] = rb[j];
        }
        __syncthreads();
#pragma unroll
        for (int kk = 0; kk < BK; kk += 32) {
            short8 af[4], bf[4];
#pragma unroll
            for (int mi = 0; mi < 4; ++mi)
                af[mi] = *(const short8*)&Al[wm*64 + mi*16 + ln][kk + quad*8];
#pragma unroll
            for (int ni = 0; ni < 4; ++ni)
                bf[ni] = *(const short8*)&Bl[wn*64 + ni*16 + ln][kk + quad*8];
#pragma unroll
            for (int mi = 0; mi < 4; ++mi)
#pragma unroll
                for (int ni = 0; ni < 4; ++ni)
                    acc[mi][ni] = __builtin_amdgcn_mfma_f32_16x16x32_bf16(
                        af[mi], bf[ni], acc[mi][ni], 0, 0, 0);
        }
    }

#pragma unroll
    for (int mi = 0; mi < 4; ++mi)
#pragma unroll
        for (int ni = 0; ni < 4; ++ni) {
            const int col = col0 + wn*64 + ni*16 + ln;
            const float bv = bias[col];
#pragma unroll
            for (int reg = 0; reg < 4; ++reg) {
                const int row = row0 + wm*64 + mi*16 + quad*4 + reg;
                out[(size_t)row * Cdim + col] = acc[mi][ni][reg] + bv;
            }
        }
}

// ---------------------------------------------------------------------------
// Kernel: tiled sliding-window attention (bf16 in, bf16 out).
// 32 q/block, 160-row K/V window in LDS, 8 lanes/query. grid (64, 24).
// ---------------------------------------------------------------------------
#define TQ   32
#define ROWS 160
#define KST  72
#define SST  168

__global__ __launch_bounds__(256) void swin_attn(
    const unsigned short* __restrict__ qbuf, const unsigned short* __restrict__ kbuf,
    const unsigned short* __restrict__ vbuf, unsigned short* __restrict__ ab)
{
    __shared__ __align__(16) unsigned short Qs[TQ][KST];
    __shared__ __align__(16) unsigned short Ks[ROWS][KST];
    __shared__ __align__(16) unsigned short Vs[ROWS][KST];
    __shared__ __align__(16) unsigned short sc[TQ][SST];

    const int t  = threadIdx.x;
    const int bh = blockIdx.y;
    const int b  = bh / Hh, h = bh % Hh;
    const int i0 = blockIdx.x * TQ;

    for (int F = t; F < 352 * 8; F += 256) {
        const int r = F >> 3, c8 = F & 7;
        const unsigned short* base = nullptr;
        unsigned short* dst;
        if (r < 32) {
            base = qbuf + ((size_t)bh * Nseq + (i0 + r)) * Dd;
            dst = &Qs[r][c8 * 8];
        } else if (r < 192) {
            const int g = i0 - HALF + (r - 32);
            if (g >= 0 && g < Nseq) base = kbuf + ((size_t)bh * Nseq + g) * Dd;
            dst = &Ks[r - 32][c8 * 8];
        } else {
            const int g = i0 - HALF + (r - 192);
            if (g >= 0 && g < Nseq) base = vbuf + ((size_t)bh * Nseq + g) * Dd;
            dst = &Vs[r - 192][c8 * 8];
        }
        uint4 v = make_uint4(0u, 0u, 0u, 0u);
        if (base) v = *(const uint4*)&base[c8 * 8];
        *(uint4*)dst = v;
    }
    __syncthreads();

    const int q = t >> 3;
    const int s = t & 7;
    const int i = i0 + q;

    float qreg[64];
#pragma unroll
    for (int c = 0; c < 8; ++c) {
        uint4 u = *(const uint4*)&Qs[q][c * 8];
        qreg[c*8+0] = lo2f(u.x); qreg[c*8+1] = hi2f(u.x);
        qreg[c*8+2] = lo2f(u.y); qreg[c*8+3] = hi2f(u.y);
        qreg[c*8+4] = lo2f(u.z); qreg[c*8+5] = hi2f(u.z);
        qreg[c*8+6] = lo2f(u.w); qreg[c*8+7] = hi2f(u.w);
    }

    float sreg[20];
    float lmax = -1e30f;
#pragma unroll
    for (int m = 0; m < 20; ++m) {
        const int j = s + 8 * m;
        const int g = i0 - HALF + j;
        const bool valid = (j >= q) && (j <= q + 2 * HALF) && (g >= 0) && (g < Nseq);
        float dot = 0.f;
#pragma unroll
        for (int c = 0; c < 8; ++c) {
            uint4 u = *(const uint4*)&Ks[j][c * 8];
            dot += qreg[c*8+0]*lo2f(u.x) + qreg[c*8+1]*hi2f(u.x)
                 + qreg[c*8+2]*lo2f(u.y) + qreg[c*8+3]*hi2f(u.y)
                 + qreg[c*8+4]*lo2f(u.z) + qreg[c*8+5]*hi2f(u.z)
                 + qreg[c*8+6]*lo2f(u.w) + qreg[c*8+7]*hi2f(u.w);
        }
        sreg[m] = valid ? dot * SCALEF : -1e30f;
        lmax = fmaxf(lmax, sreg[m]);
    }
    lmax = fmaxf(lmax, __shfl_xor(lmax, 1));
    lmax = fmaxf(lmax, __shfl_xor(lmax, 2));
    lmax = fmaxf(lmax, __shfl_xor(lmax, 4));

    float lsum = 0.f;
#pragma unroll
    for (int m = 0; m < 20; ++m) {
        const float p = (sreg[m] > -1e29f) ? __expf(sreg[m] - lmax) : 0.f;
        lsum += p;
        sc[q][s + 8 * m] = f2bf(p);
    }
    lsum += __shfl_xor(lsum, 1);
    lsum += __shfl_xor(lsum, 2);
    lsum += __shfl_xor(lsum, 4);
    const float inv = 1.f / lsum;

    __syncthreads();

    const int d0 = s * 8;
    float acc[8] = {};
    for (int m0 = 0; m0 < 20; ++m0) {
        const int jb = m0 * 8;
        if (jb + 7 < q || jb > q + 2 * HALF) continue;
        uint4 up = *(const uint4*)&sc[q][jb];
        const float pv[8] = {lo2f(up.x), hi2f(up.x), lo2f(up.y), hi2f(up.y),
                             lo2f(up.z), hi2f(up.z), lo2f(up.w), hi2f(up.w)};
#pragma unroll
        for (int jj = 0; jj < 8; ++jj) {
            uint4 uv = *(const uint4*)&Vs[jb + jj][d0];
            const float p = pv[jj];
            acc[0] += p * lo2f(uv.x); acc[1] += p * hi2f(uv.x);
            acc[2] += p * lo2f(uv.y); acc[3] += p * hi2f(uv.y);
            acc[4] += p * lo2f(uv.z); acc[5] += p * hi2f(uv.z);
            acc[6] += p * lo2f(uv.w); acc[7] += p * hi2f(uv.w);
        }
    }

    unsigned short* orow = &ab[((size_t)(b * Nseq + i)) * Cdim + h * Dd + d0];
    union { unsigned short us[8]; uint4 u; } pk;
#pragma unroll
    for (int d = 0; d < 8; ++d) pk.us[d] = f2bf(acc[d] * inv);
    *(uint4*)orow = pk.u;
}

// ---------------------------------------------------------------------------
extern "C" void kernel_launch(void* const* d_in, const int* in_sizes, int n_in,
                              void* d_out, int out_size, void* d_ws, size_t ws_size,
                              hipStream_t stream)
{
    const float* x      = (const float*)d_in[0];
    const float* w_qkv  = (const float*)d_in[1];
    const float* w_proj = (const float*)d_in[2];
    const float* b_proj = (const float*)d_in[3];
    float* out = (float*)d_out;

    // ws (bf16 shorts). Q/K/V are B*H*N*D = 3,145,728 elems EACH (r9 bug:
    // used 1,048,576 -> buffers aliased). Total 36.2 MB (<50.3 MB proven).
    const size_t QE = (size_t)Bsz * Hh * Nseq * Dd;      // 3,145,728
    unsigned short* xb  = (unsigned short*)d_ws;         // 3,145,728
    unsigned short* wb  = xb  + 3145728;                 // 1,769,472
    unsigned short* wpb = wb  + 1769472;                 //   589,824
    unsigned short* qb  = wpb + 589824;                  // QE
    unsigned short* kb  = qb  + QE;                      // QE
    unsigned short* vb  = kb  + QE;                      // QE
    unsigned short* ab  = vb  + QE;                      // 3,145,728

    f32_to_bf16<<<3145728 / 1024, 256, 0, stream>>>(x, xb, 3145728);
    f32_to_bf16<<<1769472 / 1024, 256, 0, stream>>>(w_qkv, wb, 1769472);
    f32_to_bf16<<< 589824 / 1024, 256, 0, stream>>>(w_proj, wpb, 589824);

    qkv_mfma<<<dim3((3 * Cdim) / 128, (Bsz * Nseq) / 128), 256, 0, stream>>>(
        xb, wb, qb, kb, vb);

    swin_attn<<<dim3(Nseq / TQ, Bsz * Hh), 256, 0, stream>>>(qb, kb, vb, ab);

    proj_mfma<<<dim3(Cdim / 128, (Bsz * Nseq) / 128), 256, 0, stream>>>(
        ab, wpb, b_proj, out);
}